// Round 10
// baseline (170.884 us; speedup 1.0000x reference)
//
#include <hip/hip_runtime.h>
#include <hip/hip_bf16.h>

#define NB 32
#define NA 1024
#define ND 128
#define TG 16

__device__ __forceinline__ float gelu_exact(float x) {
    return 0.5f * x * (1.0f + erff(x * 0.7071067811865476f));
}

// exact mul+add (no fma contraction) to match the np reference bit-for-bit
__device__ __forceinline__ float dist2(float ax, float ay, float bx, float by) {
    float dx = ax - bx, dy = ay - by;
    return __fadd_rn(__fmul_rn(dx, dx), __fmul_rn(dy, dy));
}

// ---------------------------------------------------------------------------
// A: clustering ONLY (isolated for per-phase profiling). One block of 1024
// threads per batch; point i -> wave i/64, lane i%64. Producer/consumer
// leader pipeline as in R6/R8, plus: fully-dead waves skip ring consumption
// and just forward done_s (early exit). Tail zeroes the sums/counts rows the
// pool will accumulate into (g < Gpad). Block NB computes the MLP(0) row.
// ---------------------------------------------------------------------------
__global__ __launch_bounds__(1024, 1) void cluster_kernel(
    const float2* __restrict__ coords, const int* __restrict__ mask,
    int* __restrict__ assigned, int* __restrict__ gcount,
    float* __restrict__ sums, float* __restrict__ counts,
    float* __restrict__ out_mask, float* __restrict__ out_a2g,
    const float* __restrict__ b1, const float* __restrict__ W2,
    const float* __restrict__ b2, float* __restrict__ empty_row)
{
    __shared__ float2 ring[NA];
    __shared__ int done_s[16];
    __shared__ int lead_cnt;

    const int tid = threadIdx.x;

    if (blockIdx.x == NB) {
        // empty row = gelu(b1) @ W2 + b2
        float* hbuf = (float*)ring;
        if (tid < ND) hbuf[tid] = gelu_exact(b1[tid]);
        __syncthreads();
        if (tid < ND) {
            float acc = b2[tid];
            for (int k = 0; k < ND; ++k) acc += hbuf[k] * W2[k * ND + tid];
            empty_row[tid] = acc;
        }
        return;
    }

    const int b = blockIdx.x;
    const int w = tid >> 6;
    const int lane = tid & 63;

    if (tid < 16) done_s[tid] = -1;
    if (tid == 0) lead_cnt = 0;

    float2 p = coords[(b << 10) + tid];
    const bool valid = mask[(b << 10) + tid] != 0;
    int asg = valid ? -1 : -2;
    bool alive = valid;
    const float thr2 = 0.05f * 0.05f;

    __syncthreads();

    int seen = 0;
    int target = (w == 0) ? 0 : -1;

    // -------- consume earlier waves' leaders --------
    while (true) {
        if (target < 0)
            target = __hip_atomic_load(&done_s[w - 1], __ATOMIC_ACQUIRE,
                                       __HIP_MEMORY_SCOPE_WORKGROUP);
        if (__ballot(alive) == 0ULL) {         // wave fully decided:
            if (target >= 0) { seen = target; break; }   // skip the ring
        } else {
            int c = __hip_atomic_load(&lead_cnt, __ATOMIC_ACQUIRE,
                                      __HIP_MEMORY_SCOPE_WORKGROUP);
            if (c > seen) {
                do {
                    float2 l = ring[seen];
                    float d2 = dist2(p.x, p.y, l.x, l.y);
                    if (alive && d2 < thr2) { asg = seen; alive = false; }
                    ++seen;
                } while (seen < c);
                continue;
            }
            if (target >= 0 && seen >= target) break;
        }
        __builtin_amdgcn_s_sleep(1);
    }

    // -------- produce this wave's leaders --------
    __builtin_amdgcn_s_setprio(1);
    unsigned long long bal;
    while ((bal = __ballot(alive)) != 0ULL) {
        const int L = (int)__builtin_ctzll(bal);
        const float lx = __builtin_bit_cast(float,
            __builtin_amdgcn_readlane(__builtin_bit_cast(int, p.x), L));
        const float ly = __builtin_bit_cast(float,
            __builtin_amdgcn_readlane(__builtin_bit_cast(int, p.y), L));
        float d2 = dist2(p.x, p.y, lx, ly);
        bool take = alive && (d2 < thr2);
        if (take) { asg = seen; alive = false; }
        if (lane == 0) ring[seen] = make_float2(lx, ly);
        ++seen;
        if (lane == 0)
            __hip_atomic_store(&lead_cnt, seen, __ATOMIC_RELEASE,
                               __HIP_MEMORY_SCOPE_WORKGROUP);
    }
    if (lane == 0)
        __hip_atomic_store(&done_s[w], seen, __ATOMIC_RELEASE,
                           __HIP_MEMORY_SCOPE_WORKGROUP);
    __builtin_amdgcn_s_setprio(0);

    __syncthreads();
    const int G = lead_cnt;

    // -------- outputs --------
    assigned[(b << 10) + tid] = asg;
    out_a2g[(b << 10) + tid] = (asg == -2) ? -1.0f : (float)asg;
    out_mask[(b << 10) + tid] = (tid < G) ? 1.0f : 0.0f;
    if (tid == 0) gcount[b] = G;

    // -------- zero the pool accumulators for g < Gpad --------
    const int Gpad = (G + TG - 1) & ~(TG - 1);
    float4* s4 = (float4*)(sums + (((size_t)b) << 10) * ND);
    for (int i = tid; i < Gpad * 32; i += 1024)
        s4[i] = make_float4(0.f, 0.f, 0.f, 0.f);
    if (tid < Gpad) counts[(b << 10) + tid] = 0.0f;
}

// ---------------------------------------------------------------------------
// D: flood-fill out0 with the MLP(0) row (covers all g >= G rows; heavy
// blocks of C overwrite g < G). No LDS -> full occupancy.
// ---------------------------------------------------------------------------
__global__ __launch_bounds__(256) void fill_kernel(
    const float* __restrict__ empty_row, float4* __restrict__ out0)
{
    const int idx = blockIdx.x * 256 + threadIdx.x;   // B*A*32 float4s
    float4 r = ((const float4*)empty_row)[idx & 31];
    out0[idx] = r;
}

// ---------------------------------------------------------------------------
// B: pooling via flat global f32 atomics (massively parallel, proven cheap).
// One thread per (agent, dim-quad).
// ---------------------------------------------------------------------------
__global__ __launch_bounds__(256) void pool_kernel(
    const float4* __restrict__ emb, const int* __restrict__ assigned,
    float* __restrict__ sums, float* __restrict__ counts)
{
    const int idx = blockIdx.x * 256 + threadIdx.x;   // B*A*32 threads
    const int al = idx >> 5;                          // b*A + a
    const int dq = idx & 31;
    const int g = assigned[al];
    if (g < 0) return;
    const int b = al >> 10;
    float4 e = emb[(size_t)al * 32 + dq];
    float* s = sums + (((size_t)((b << 10) + g)) * ND) + dq * 4;
    atomicAdd(s + 0, e.x);
    atomicAdd(s + 1, e.y);
    atomicAdd(s + 2, e.z);
    atomicAdd(s + 3, e.w);
    if (dq == 0) atomicAdd(&counts[(b << 10) + g], 1.0f);
}

// ---------------------------------------------------------------------------
// C: 2-layer MLP on real groups only (g0 >= G blocks exit immediately;
// D already wrote their rows). Tokens = sums/max(cnt,1) staged to LDS.
// ---------------------------------------------------------------------------
__global__ __launch_bounds__(256, 2) void mlp_kernel(
    const float* __restrict__ sums, const float* __restrict__ counts,
    const int* __restrict__ gcount,
    const float4* __restrict__ W1, const float* __restrict__ b1,
    const float4* __restrict__ W2, const float* __restrict__ b2,
    float* __restrict__ out0)
{
    const int b = blockIdx.y;
    const int g0 = blockIdx.x * TG;
    const int tid = threadIdx.x;
    if (g0 >= gcount[b]) return;                       // D covered these rows
    float* ob = out0 + ((size_t)(b << 10) + g0) * ND;

    __shared__ float4 Wl[4096];      // 64 KB
    __shared__ float tok[TG][ND];    // 8 KB: tokens, then h

    {   // tokens = sums / max(cnt,1)   (g >= G rows were zeroed -> MLP(0))
        const float4* s4 = (const float4*)(sums + ((size_t)(b << 10) + g0) * ND);
        float4* tdst = (float4*)&tok[0][0];
#pragma unroll
        for (int i = 0; i < 2; ++i) {
            int l = tid + i * 256;           // 0..511, 32 float4 per group
            float c = fmaxf(counts[(b << 10) + g0 + (l >> 5)], 1.0f);
            float4 v = s4[l];
            tdst[l] = make_float4(v.x / c, v.y / c, v.z / c, v.w / c);
        }
    }
#pragma unroll
    for (int i = 0; i < 16; ++i) Wl[tid + i * 256] = W1[tid + i * 256];
    __syncthreads();

    const int jq = tid & 31;
    const int gs = tid >> 5;
    float acc[2][4];
#pragma unroll
    for (int jj = 0; jj < 4; ++jj) { acc[0][jj] = 0.0f; acc[1][jj] = 0.0f; }

#pragma unroll 4
    for (int dd = 0; dd < ND; ++dd) {
        float4 wv = Wl[dd * 32 + jq];
        float t0 = tok[gs][dd];
        float t1 = tok[gs + 8][dd];
        acc[0][0] += t0 * wv.x; acc[0][1] += t0 * wv.y;
        acc[0][2] += t0 * wv.z; acc[0][3] += t0 * wv.w;
        acc[1][0] += t1 * wv.x; acc[1][1] += t1 * wv.y;
        acc[1][2] += t1 * wv.z; acc[1][3] += t1 * wv.w;
    }
    float4 bb = ((const float4*)b1)[jq];
    __syncthreads();   // all layer-1 tok reads done before overwrite
    {
        float4 h;
        h.x = gelu_exact(acc[0][0] + bb.x);
        h.y = gelu_exact(acc[0][1] + bb.y);
        h.z = gelu_exact(acc[0][2] + bb.z);
        h.w = gelu_exact(acc[0][3] + bb.w);
        *(float4*)&tok[gs][jq * 4] = h;
        h.x = gelu_exact(acc[1][0] + bb.x);
        h.y = gelu_exact(acc[1][1] + bb.y);
        h.z = gelu_exact(acc[1][2] + bb.z);
        h.w = gelu_exact(acc[1][3] + bb.w);
        *(float4*)&tok[gs + 8][jq * 4] = h;
    }
#pragma unroll
    for (int i = 0; i < 16; ++i) Wl[tid + i * 256] = W2[tid + i * 256];
    __syncthreads();

#pragma unroll
    for (int jj = 0; jj < 4; ++jj) { acc[0][jj] = 0.0f; acc[1][jj] = 0.0f; }
#pragma unroll 4
    for (int dd = 0; dd < ND; ++dd) {
        float4 wv = Wl[dd * 32 + jq];
        float t0 = tok[gs][dd];
        float t1 = tok[gs + 8][dd];
        acc[0][0] += t0 * wv.x; acc[0][1] += t0 * wv.y;
        acc[0][2] += t0 * wv.z; acc[0][3] += t0 * wv.w;
        acc[1][0] += t1 * wv.x; acc[1][1] += t1 * wv.y;
        acc[1][2] += t1 * wv.z; acc[1][3] += t1 * wv.w;
    }
    float4 cbv = ((const float4*)b2)[jq];
    {
        float4 o;
        o.x = acc[0][0] + cbv.x; o.y = acc[0][1] + cbv.y;
        o.z = acc[0][2] + cbv.z; o.w = acc[0][3] + cbv.w;
        *(float4*)&ob[(size_t)gs * ND + jq * 4] = o;
        o.x = acc[1][0] + cbv.x; o.y = acc[1][1] + cbv.y;
        o.z = acc[1][2] + cbv.z; o.w = acc[1][3] + cbv.w;
        *(float4*)&ob[(size_t)(gs + 8) * ND + jq * 4] = o;
    }
}

extern "C" void kernel_launch(void* const* d_in, const int* in_sizes, int n_in,
                              void* d_out, int out_size, void* d_ws, size_t ws_size,
                              hipStream_t stream) {
    const float* emb    = (const float*)d_in[0];   // [B,A,D]
    const float* coords = (const float*)d_in[1];   // [B,A,2]
    const int*   mask   = (const int*)d_in[2];     // [B,A]
    const float* W1     = (const float*)d_in[3];   // [D,D]
    const float* b1     = (const float*)d_in[4];   // [D]
    const float* W2     = (const float*)d_in[5];   // [D,D]
    const float* b2     = (const float*)d_in[6];   // [D]

    float* out0 = (float*)d_out;                    // [B,A,D]
    float* out1 = out0 + (size_t)NB * NA * ND;      // group_mask
    float* out2 = out1 + (size_t)NB * NA;           // agent_to_group

    // workspace: sums, counts, assigned, gcount, empty_row
    float* ws_sums   = (float*)d_ws;                        // B*A*D
    float* ws_counts = ws_sums + (size_t)NB * NA * ND;      // B*A
    int*   ws_asg    = (int*)(ws_counts + (size_t)NB * NA); // B*A
    int*   ws_gcnt   = ws_asg + (size_t)NB * NA;            // B
    float* ws_empty  = (float*)(ws_gcnt + NB);              // D

    cluster_kernel<<<NB + 1, 1024, 0, stream>>>(
        (const float2*)coords, mask, ws_asg, ws_gcnt,
        ws_sums, ws_counts, out1, out2,
        b1, W2, b2, ws_empty);
    fill_kernel<<<NB * NA * 32 / 256, 256, 0, stream>>>(
        ws_empty, (float4*)out0);
    pool_kernel<<<NB * NA * 32 / 256, 256, 0, stream>>>(
        (const float4*)emb, ws_asg, ws_sums, ws_counts);
    mlp_kernel<<<dim3(NA / TG, NB), 256, 0, stream>>>(
        ws_sums, ws_counts, ws_gcnt,
        (const float4*)W1, b1, (const float4*)W2, b2, out0);
}